// Round 6
// baseline (442.682 us; speedup 1.0000x reference)
//
#include <hip/hip_runtime.h>

// MultiHeadAttention: B=8, C=256, H=8, D=32, T=16, P=1024, F=D*T=512
// Pipeline:
//  k_wconv : Wk/Wq/Wv fp32 -> Wall[768][256] bf16 (chunk-swizzled by o&7)
//  k_xt    : x fp32 [b][c][n] -> Xbf [b][n(16384)][c(256)] bf16 (chunk-swizzled by n&7)
//  k_proj2 : GEMM Wall x Xbf -> Kb,Qb,Vb [bh][p][512] bf16 (swizzled); grid 512,
//            each block loops otile 0..2 (NT=12 continuous K-steps)
//  k_egemm : Pt[bh][q][p] = bf16(exp2(QK^T/S)) + fused partial Z; grid 256,
//            q-tile fixed, loops p0 over 4 segments (NT=32). SWAPPED mfma
//            operands -> C rows=p, cols=q -> 8B Pt stores, Z via shfl.
//  k_zfinal: RZ[bh][p] = 1/sum(8 Zpart slices)
//  k_vt    : Vb [p][f] --transpose+scale by RZ[p]--> Vt [bh][f][1024] bf16
//  k_pv    : out = Pt x Vt'; grid 256, loops f0 (NT=32)
// GEMM core: 8-phase counted-vmcnt schedule running CONTINUOUSLY across
// segments; per-segment epilogue after ph8 + vmcnt(0) drain (stores count
// in vmcnt on CDNA; drain keeps the ledger strict-safe).

typedef unsigned short u16;
typedef unsigned int u32;
typedef __attribute__((ext_vector_type(8))) short bfx8;
typedef __attribute__((ext_vector_type(4))) float fx4;

constexpr float KC1 = 1.4426950408889634f / 22.627416997969522f; // log2(e)/sqrt(512)

__device__ __forceinline__ u16 f2bf(float f) {
  u32 u = __builtin_bit_cast(u32, f);
  return (u16)((u + 0x7fffu + ((u >> 16) & 1u)) >> 16);
}
__device__ __forceinline__ float bf2f(u16 v) {
  return __builtin_bit_cast(float, (u32)v << 16);
}
__device__ __forceinline__ fx4 mfma16(bfx8 a, bfx8 b, fx4 c) {
  return __builtin_amdgcn_mfma_f32_16x16x32_bf16(a, b, c, 0, 0, 0);
}
typedef __attribute__((address_space(1))) const unsigned int* as1p;
typedef __attribute__((address_space(3))) unsigned int* as3p;
__device__ __forceinline__ void gll16(const void* g, void* l) {
  __builtin_amdgcn_global_load_lds((as1p)g, (as3p)l, 16, 0, 0);
}
__device__ __forceinline__ void midbar_() { __builtin_amdgcn_s_barrier(); }
__device__ __forceinline__ void pend_() {
  __builtin_amdgcn_s_barrier();
  __builtin_amdgcn_sched_barrier(0);
}
#define VMC4 do { asm volatile("s_waitcnt vmcnt(4)" ::: "memory"); \
                  __builtin_amdgcn_sched_barrier(0); } while (0)
#define VMC0 do { asm volatile("s_waitcnt vmcnt(0)" ::: "memory"); \
                  __builtin_amdgcn_sched_barrier(0); } while (0)

// ---- continuous 8-phase 256x256 GEMM core over NT K-tiles of 64 ----
// Segment s = t>>SL; A col base = (t&mask)*64 + (t>>SL)*ASTR (elements), B same
// with BSTR. epi(s) called after each segment's last tile; must reset acc and
// must not touch LDS.
template <bool SWAP, int NT, int SL, int LK, int ASTR, int BSTR, typename Epi>
__device__ __forceinline__ void gemm8m(const u16* __restrict__ Ag,
                                       const u16* __restrict__ Bg,
                                       u16* lds, fx4 (&acc)[2][4][2][2],
                                       int wv, int lane, Epi&& epi) {
  const int l15 = lane & 15, kg = lane >> 4, l7 = lane & 7;
  const int wr = wv >> 2, wn = wv & 3;
  const int rsub = lane >> 3, csub = (lane & 7) * 8;
  constexpr int A0 = 0, A1 = 16384, B0 = 32768, B1 = 49152;
  constexpr int TM = (1 << SL) - 1;
  bfx8 af[4][2], bf[2][2][2];

  auto stg = [&](const u16* g, int sstr, int ldsoff, int t, int half) {
    const u16* gp = g + (size_t)(t >> SL) * (size_t)sstr + (t & TM) * 64
                  + (size_t)(half * 128 + wv * 16 + rsub) * LK + csub;
    u16* lp = lds + ldsoff + half * 8192 + wv * 1024;
    gll16(gp, lp);
    gll16(gp + (size_t)8 * LK, lp + 512);
  };
  auto LA = [&](int boff, int mh) {
    const u16* base = lds + boff + mh * 8192 + wr * 4096;
#pragma unroll
    for (int mt = 0; mt < 4; ++mt)
#pragma unroll
      for (int kk = 0; kk < 2; ++kk)
        af[mt][kk] = *(const bfx8*)(base + (mt * 16 + l15) * 64 + (((kk << 2) + kg) ^ l7) * 8);
  };
  auto LB = [&](int boff, int nh) {
    const u16* base = lds + boff + nh * 8192 + wn * 2048;
#pragma unroll
    for (int nt = 0; nt < 2; ++nt)
#pragma unroll
      for (int kk = 0; kk < 2; ++kk)
        bf[nh][nt][kk] = *(const bfx8*)(base + (nt * 16 + l15) * 64 + (((kk << 2) + kg) ^ l7) * 8);
  };
  auto MM = [&](int mh, int nh) {
    __builtin_amdgcn_s_setprio(1);
#pragma unroll
    for (int mt = 0; mt < 4; ++mt)
#pragma unroll
      for (int nt = 0; nt < 2; ++nt)
#pragma unroll
        for (int kk = 0; kk < 2; ++kk) {
          if constexpr (SWAP)
            acc[mh][mt][nh][nt] = mfma16(bf[nh][nt][kk], af[mt][kk], acc[mh][mt][nh][nt]);
          else
            acc[mh][mt][nh][nt] = mfma16(af[mt][kk], bf[nh][nt][kk], acc[mh][mt][nh][nt]);
        }
    __builtin_amdgcn_s_setprio(0);
  };

  // prologue: tile0 full, A-lo(1), B-hi(1); vmcnt(4) -> tile0 landed.
  stg(Ag, ASTR, A0, 0, 0); stg(Ag, ASTR, A0, 0, 1);
  stg(Bg, BSTR, B0, 0, 0); stg(Bg, BSTR, B0, 0, 1);
  stg(Ag, ASTR, A1, 1, 0); stg(Bg, BSTR, B1, 1, 1);
  VMC4;
  pend_();

#pragma unroll 1
  for (int i = 0; i < NT / 2; ++i) {
    const int t = 2 * i;
    const bool m2 = (t + 2 < NT), m3 = (t + 3 < NT);
    // ph1: Q(0,0) of tile t
    LA(A0, 0); LB(B0, 0);
    stg(Ag, ASTR, A1, t + 1, 1);
    midbar_(); MM(0, 0); pend_();
    // ph2: Q(0,1)
    LB(B0, 1);
    stg(Bg, BSTR, B1, t + 1, 0);
    midbar_(); MM(0, 1); pend_();
    // ph3: Q(1,1)
    LA(A0, 1);
    if (m2) stg(Ag, ASTR, A0, t + 2, 0);
    midbar_(); MM(1, 1); pend_();
    // ph4: Q(1,0)
    if (m2) stg(Bg, BSTR, B0, t + 2, 1);
    midbar_(); MM(1, 0);
    if (m2) { VMC4; } else { VMC0; }
    pend_();
    // ph5: Q(0,0) of tile t+1
    LA(A1, 0); LB(B1, 0);
    if (m2) stg(Ag, ASTR, A0, t + 2, 1);
    midbar_(); MM(0, 0); pend_();
    // ph6: Q(0,1)
    LB(B1, 1);
    if (m2) stg(Bg, BSTR, B0, t + 2, 0);
    midbar_(); MM(0, 1); pend_();
    // ph7: Q(1,1)
    LA(A1, 1);
    if (m3) stg(Ag, ASTR, A1, t + 3, 0);
    midbar_(); MM(1, 1); pend_();
    // ph8: Q(1,0)
    if (m3) stg(Bg, BSTR, B1, t + 3, 1);
    midbar_(); MM(1, 0);
    if (m2) { VMC4; }
    pend_();
    if (((t + 2) & TM) == 0) {
      epi((t + 1) >> SL);
      if (t + 2 < NT) { VMC0; }   // drain epi stores + prefetches; ledger reset-safe
    }
  }
}

// ---------------- W fp32 -> Wall bf16 swizzled ----------------
__global__ __launch_bounds__(256) void k_wconv(const float* __restrict__ Wk,
                                               const float* __restrict__ Wq,
                                               const float* __restrict__ Wv,
                                               u16* __restrict__ Wall) {
  int blk = blockIdx.x;          // 96 = 3 proj * 32
  int pr = blk >> 5;
  const float* src = (pr == 0) ? Wk : ((pr == 1) ? Wq : Wv);
  int oc = (blk & 31) * 8 + (threadIdx.x >> 5);
  int Cc = threadIdx.x & 31;
  const float4* s4 = (const float4*)(src + oc * 256 + Cc * 8);
  float4 a = s4[0], b = s4[1];
  alignas(16) u16 t[8] = {f2bf(a.x), f2bf(a.y), f2bf(a.z), f2bf(a.w),
                          f2bf(b.x), f2bf(b.y), f2bf(b.z), f2bf(b.w)};
  int o = pr * 256 + oc;
  int pos = (Cc & ~7) + ((Cc & 7) ^ (o & 7));
  *(uint4*)(Wall + o * 256 + pos * 8) = *(const uint4*)t;
}

// ---------------- x -> Xbf transpose/convert ----------------
__global__ __launch_bounds__(256) void k_xt(const float* __restrict__ x,
                                            u16* __restrict__ Xbf) {
  __shared__ u16 Xs[128 * 256]; // [n][c] bf16, 64 KiB
  int b = blockIdx.x >> 7;
  int n0 = (blockIdx.x & 127) * 128;
  int tid = threadIdx.x;
  int ng = tid & 31, cgrp = tid >> 5;
  const float* xb = x + (size_t)b * 4194304 + n0 + ng * 4;
#pragma unroll
  for (int it = 0; it < 4; ++it) {
    int Cc = cgrp + it * 8;       // c-chunk 0..31
    float4 v[8];
#pragma unroll
    for (int i = 0; i < 8; ++i)
      v[i] = *(const float4*)(xb + (size_t)(Cc * 8 + i) * 16384);
#pragma unroll
    for (int j = 0; j < 4; ++j) {
      int n = ng * 4 + j;
      alignas(16) u16 c8[8];
#pragma unroll
      for (int i = 0; i < 8; ++i) c8[i] = f2bf(((const float*)&v[i])[j]);
      int pos = (Cc & ~7) + ((Cc & 7) ^ (n & 7));
      *(uint4*)&Xs[n * 256 + pos * 8] = *(const uint4*)c8;
    }
  }
  __syncthreads();
  u16* xo = Xbf + (size_t)b * 4194304 + (size_t)n0 * 256;
#pragma unroll
  for (int it = 0; it < 16; ++it) {
    int idx = tid + it * 256;
    int n = idx >> 5, chp = idx & 31;
    uint4 v = *(const uint4*)&Xs[n * 256 + chp * 8];
    *(uint4*)&xo[(size_t)n * 256 + chp * 8] = v;
  }
}

// ---------------- fused 3-projection GEMM ----------------
// grid 512 (n-groups), 512 thr; block loops otile 0..2, NT=12 continuous.
__global__ __launch_bounds__(512) void k_proj2(const u16* __restrict__ Xbf,
                                               const u16* __restrict__ Wall,
                                               u16* __restrict__ Kb, u16* __restrict__ Qb,
                                               u16* __restrict__ Vb) {
  __shared__ u16 lds[65536];
  int bid = blockIdx.x;
  int vid = (bid & 7) * 64 + (bid >> 3);
  int b = vid >> 6, ntile = vid & 63;
  int tid = threadIdx.x, lane = tid & 63, wv = tid >> 6;
  int l15 = lane & 15, kg = lane >> 4;
  int wr = wv >> 2, wn = wv & 3;
  const u16* Ag = Wall;
  const u16* Bg = Xbf + (size_t)b * 4194304 + (size_t)ntile * 65536;
  fx4 acc[2][4][2][2];
#pragma unroll
  for (int mh = 0; mh < 2; ++mh)
#pragma unroll
    for (int mt = 0; mt < 4; ++mt)
#pragma unroll
      for (int nh = 0; nh < 2; ++nh)
#pragma unroll
        for (int nt = 0; nt < 2; ++nt) acc[mh][mt][nh][nt] = (fx4)0.0f;

  auto epi = [&](int s) {
    u16* dst = (s == 0) ? Kb : ((s == 1) ? Qb : Vb);
#pragma unroll
    for (int mh = 0; mh < 2; ++mh)
#pragma unroll
      for (int mt = 0; mt < 4; ++mt) {
        int o = mh * 128 + wr * 64 + mt * 16 + kg * 4;
        int h = o >> 5;
        size_t bhro = (size_t)(b * 8 + h) * 524288;
#pragma unroll
        for (int nh = 0; nh < 2; ++nh)
#pragma unroll
          for (int nt = 0; nt < 2; ++nt) {
            int p = ntile * 16 + nh * 8 + wn * 2 + nt;
            size_t ro = bhro + (size_t)p * 512;
            int p7 = p & 7;
#pragma unroll
            for (int j = 0; j < 4; ++j) {
              int f = ((o & 31) + j) * 16 + l15;
              int ch = (f >> 3) ^ p7;
              dst[ro + ch * 8 + (f & 7)] = f2bf(acc[mh][mt][nh][nt][j]);
            }
            acc[mh][mt][nh][nt] = (fx4)0.0f;
          }
      }
  };

  gemm8m<false, 12, 2, 256, 65536, 0>(Ag, Bg, lds, acc, wv, lane, epi);
}

// ---------------- E-GEMM + exp2 -> Pt, fused partial Z ----------------
// grid 256 (64 bh x 4 q-tiles), 512 thr; block loops p0 over 4 segs, NT=32.
// SWAPPED operands: C row = p (kg*4+j), col = q (l15).
__global__ __launch_bounds__(512) void k_egemm(const u16* __restrict__ Qb,
                                               const u16* __restrict__ Kb,
                                               u16* __restrict__ Pt,
                                               float* __restrict__ Zpart) {
  __shared__ u16 lds[65536];
  int bid = blockIdx.x;
  int vid = (bid & 7) * 32 + (bid >> 3);
  int bh = vid >> 2, qt = vid & 3;
  int q0 = qt * 256;
  int tid = threadIdx.x, lane = tid & 63, wv = tid >> 6;
  int l15 = lane & 15, kg = lane >> 4;
  int wr = wv >> 2, wn = wv & 3;
  const u16* Ag = Qb + (size_t)bh * 524288 + (size_t)q0 * 512;
  const u16* Bg = Kb + (size_t)bh * 524288;
  size_t pbase = (size_t)bh * 1048576;
  fx4 acc[2][4][2][2];
#pragma unroll
  for (int mh = 0; mh < 2; ++mh)
#pragma unroll
    for (int mt = 0; mt < 4; ++mt)
#pragma unroll
      for (int nh = 0; nh < 2; ++nh)
#pragma unroll
        for (int nt = 0; nt < 2; ++nt) acc[mh][mt][nh][nt] = (fx4)0.0f;

  auto epi = [&](int s) {
    float zac[2][2][4];
#pragma unroll
    for (int nh = 0; nh < 2; ++nh)
#pragma unroll
      for (int nt = 0; nt < 2; ++nt)
#pragma unroll
        for (int j = 0; j < 4; ++j) zac[nh][nt][j] = 0.f;
#pragma unroll
    for (int mh = 0; mh < 2; ++mh)
#pragma unroll
      for (int mt = 0; mt < 4; ++mt) {
        int q = q0 + mh * 128 + wr * 64 + mt * 16 + l15;
        size_t qrow = pbase + (size_t)q * 1024;
        int q7 = l15 & 7;
#pragma unroll
        for (int nh = 0; nh < 2; ++nh)
#pragma unroll
          for (int nt = 0; nt < 2; ++nt) {
            int p4 = s * 256 + nh * 128 + wn * 32 + nt * 16 + kg * 4;
            alignas(8) u16 e4[4];
#pragma unroll
            for (int j = 0; j < 4; ++j) {
              float e = exp2f(acc[mh][mt][nh][nt][j] * KC1);
              zac[nh][nt][j] += e;
              e4[j] = f2bf(e);
            }
            int ch = (p4 >> 3) ^ q7;
            *(unsigned long long*)(Pt + qrow + ch * 8 + (p4 & 7)) =
                *(const unsigned long long*)e4;
            acc[mh][mt][nh][nt] = (fx4)0.0f;
          }
      }
    // reduce z over the 16 q-lanes (l15) of each kg group
#pragma unroll
    for (int nh = 0; nh < 2; ++nh)
#pragma unroll
      for (int nt = 0; nt < 2; ++nt)
#pragma unroll
        for (int j = 0; j < 4; ++j) {
          float v = zac[nh][nt][j];
          v += __shfl_xor(v, 1);
          v += __shfl_xor(v, 2);
          v += __shfl_xor(v, 4);
          v += __shfl_xor(v, 8);
          zac[nh][nt][j] = v;
        }
    if (l15 == 0) {
      size_t zb = (size_t)(qt * 2 + wr) * 65536 + (size_t)bh * 1024;
#pragma unroll
      for (int nh = 0; nh < 2; ++nh)
#pragma unroll
        for (int nt = 0; nt < 2; ++nt) {
          int p4 = s * 256 + nh * 128 + wn * 32 + nt * 16 + kg * 4;
          float4 zv;
          zv.x = zac[nh][nt][0]; zv.y = zac[nh][nt][1];
          zv.z = zac[nh][nt][2]; zv.w = zac[nh][nt][3];
          *(float4*)&Zpart[zb + p4] = zv;
        }
    }
  };

  gemm8m<true, 32, 3, 512, 0, 131072>(Ag, Bg, lds, acc, wv, lane, epi);
}

__global__ __launch_bounds__(256) void k_zfinal(const float* __restrict__ Zpart,
                                                float* __restrict__ RZ) {
  int idx = blockIdx.x * 256 + threadIdx.x; // 65536
  float s = 0.f;
#pragma unroll
  for (int k = 0; k < 8; ++k) s += Zpart[(size_t)k * 65536 + idx];
  RZ[idx] = 1.0f / s;
}

// ---------------- Vb [p][f] -> Vt [f][p] with 1/Z scale ----------------
__global__ __launch_bounds__(256) void k_vt(const u16* __restrict__ Vb,
                                            const float* __restrict__ RZ,
                                            u16* __restrict__ Vt) {
  __shared__ u16 Vl[64 * 512];
  int bh = blockIdx.x >> 4;
  int ptile = blockIdx.x & 15;
  int tid = threadIdx.x;
  const u16* src = Vb + (size_t)bh * 524288 + (size_t)ptile * 32768;
#pragma unroll
  for (int it = 0; it < 16; ++it) {
    int idx = tid + it * 256;
    int pl = idx >> 6, g = idx & 63;
    float rz = RZ[bh * 1024 + ptile * 64 + pl];
    uint4 v = *(const uint4*)&src[(size_t)pl * 512 + g * 8];
    int cf = g ^ (pl & 7);   // unswizzle: logical f-chunk
    u32 w[4] = {v.x, v.y, v.z, v.w};
    alignas(16) u16 c8[8];
#pragma unroll
    for (int i = 0; i < 4; ++i) {
      c8[2 * i]     = f2bf(bf2f((u16)w[i]) * rz);
      c8[2 * i + 1] = f2bf(bf2f((u16)(w[i] >> 16)) * rz);
    }
    *(uint4*)&Vl[pl * 512 + cf * 8] = *(const uint4*)c8;
  }
  __syncthreads();
  u16* dst = Vt + (size_t)bh * 524288;
#pragma unroll
  for (int it = 0; it < 16; ++it) {
    int f = (tid & 63) + (it & 7) * 64;
    int pc = (tid >> 6) * 2 + (it >> 3);
    int base = pc * 8 * 512 + f;
    u32 x0 = (u32)Vl[base] | ((u32)Vl[base + 512] << 16);
    u32 x1 = (u32)Vl[base + 1024] | ((u32)Vl[base + 1536] << 16);
    u32 x2 = (u32)Vl[base + 2048] | ((u32)Vl[base + 2560] << 16);
    u32 x3 = (u32)Vl[base + 3072] | ((u32)Vl[base + 3584] << 16);
    uint4 pk; pk.x = x0; pk.y = x1; pk.z = x2; pk.w = x3;
    int col = ptile * 8 + (pc ^ (f & 7));
    *(uint4*)&dst[(size_t)f * 1024 + col * 8] = pk;
  }
}

// ---------------- PV-GEMM -> out ----------------
// grid 256 (64 bh x 4 q-tiles), 512 thr; block loops f0 over 2 segs, NT=32.
__global__ __launch_bounds__(512) void k_pv(const u16* __restrict__ Pt,
                                            const u16* __restrict__ Vt,
                                            float* __restrict__ out) {
  __shared__ u16 lds[65536];
  int bid = blockIdx.x;
  int vid = (bid & 7) * 32 + (bid >> 3);
  int bh = vid >> 2, qt = vid & 3;
  int q0 = qt * 256;
  int tid = threadIdx.x, lane = tid & 63, wv = tid >> 6;
  int l15 = lane & 15, kg = lane >> 4;
  int wr = wv >> 2, wn = wv & 3;
  const u16* Ag = Pt + (size_t)bh * 1048576 + (size_t)q0 * 1024;
  const u16* Bg = Vt + (size_t)bh * 524288;
  fx4 acc[2][4][2][2];
#pragma unroll
  for (int mh = 0; mh < 2; ++mh)
#pragma unroll
    for (int mt = 0; mt < 4; ++mt)
#pragma unroll
      for (int nh = 0; nh < 2; ++nh)
#pragma unroll
        for (int nt = 0; nt < 2; ++nt) acc[mh][mt][nh][nt] = (fx4)0.0f;

  auto epi = [&](int s) {
#pragma unroll
    for (int mh = 0; mh < 2; ++mh)
#pragma unroll
      for (int mt = 0; mt < 4; ++mt) {
        int qb_ = q0 + mh * 128 + wr * 64 + mt * 16 + kg * 4;
#pragma unroll
        for (int nh = 0; nh < 2; ++nh)
#pragma unroll
          for (int nt = 0; nt < 2; ++nt) {
            int f = s * 256 + nh * 128 + wn * 32 + nt * 16 + l15;
            int d = f >> 4, t = f & 15;
            size_t cb = (size_t)(bh * 32 + d) * 16384 + t;
#pragma unroll
            for (int j = 0; j < 4; ++j)
              out[cb + (size_t)(qb_ + j) * 16] = acc[mh][mt][nh][nt][j];
            acc[mh][mt][nh][nt] = (fx4)0.0f;
          }
      }
  };

  gemm8m<false, 32, 4, 1024, 0, 262144>(Ag, Bg, lds, acc, wv, lane, epi);
}

extern "C" void kernel_launch(void* const* d_in, const int* in_sizes, int n_in,
                              void* d_out, int out_size, void* d_ws, size_t ws_size,
                              hipStream_t stream) {
  (void)in_sizes; (void)n_in; (void)out_size; (void)ws_size;
  const float* x  = (const float*)d_in[0];
  const float* Wk = (const float*)d_in[1];
  const float* Wq = (const float*)d_in[2];
  const float* Wv = (const float*)d_in[3];
  float* out = (float*)d_out;

  u16* Kb  = (u16*)d_ws;                  // [ 0, 64) MiB  [64 bh][1024 p][512 f]
  u16* Qb  = Kb + 33554432;               // [64,128) MiB
  u16* Vb  = Qb + 33554432;               // [128,192) MiB
  u16* Xbf = Vb + 33554432;               // [192,256) MiB [8 b][16384 n][256 c]
  u16* Pt  = Xbf;                         // [192,320) MiB (overlays dead Xbf)
  u16* Vt  = Qb;                          // [64,128) MiB  (overlays dead Qb)
  float* Zpart = (float*)(Kb + 167772160);// 320 MiB: [8][64][1024]
  float* RZ = Zpart + 524288;             // [64][1024]
  u16* Wall = (u16*)(RZ + 65536);         // [768][256]

  k_wconv<<<96, 256, 0, stream>>>(Wk, Wq, Wv, Wall);
  k_xt<<<1024, 256, 0, stream>>>(x, Xbf);
  k_proj2<<<512, 512, 0, stream>>>(Xbf, Wall, Kb, Qb, Vb);
  k_egemm<<<256, 512, 0, stream>>>(Qb, Kb, Pt, Zpart);
  k_zfinal<<<256, 256, 0, stream>>>(Zpart, RZ);
  k_vt<<<1024, 256, 0, stream>>>(Vb, RZ, Vt);
  k_pv<<<256, 512, 0, stream>>>(Pt, Vt, out);
}

// Round 7
// 431.001 us; speedup vs baseline: 1.0271x; 1.0271x over previous
//
#include <hip/hip_runtime.h>

// MultiHeadAttention: B=8, C=256, H=8, D=32, T=16, P=1024, F=D*T=512
//  k_wconv : W fp32 -> Wall[768][256] bf16 (chunk-swizzled by o&7)
//  k_xt    : x fp32 [b][c][n] -> Xbf [b][n][c] bf16 (chunk-swizzled by n&7)
//  k_proj2 : GEMM Wall x Xbf -> Kb,Qb,Vb [bh][p][512] (round-5 8-phase core)
//  k_egemm : Pt[bh][q][p] = bf16(exp2(QK^T/S)) + fused partial Z (16 slices)
//            NEW gemm_rp core: 256x128 tile, 4-phase register pipeline
//            (reads for phase p+1 issued during phase p -> ds_read||MFMA).
//  k_zfinal: RZ[bh][p] = 1/sum(16 Zpart slices)
//  k_vt    : Vb [p][f] -> Vt [bh][f][1024] with 1/Z[p] folded in
//  k_pv    : out = Pt x Vt' (gemm_rp core) -> d_out fp32

typedef unsigned short u16;
typedef unsigned int u32;
typedef unsigned long long u64;
typedef __attribute__((ext_vector_type(8))) short bfx8;
typedef __attribute__((ext_vector_type(4))) float fx4;

constexpr float KC1 = 1.4426950408889634f / 22.627416997969522f; // log2(e)/sqrt(512)

__device__ __forceinline__ u16 f2bf(float f) {
  u32 u = __builtin_bit_cast(u32, f);
  return (u16)((u + 0x7fffu + ((u >> 16) & 1u)) >> 16);
}
__device__ __forceinline__ float bf2f(u16 v) {
  return __builtin_bit_cast(float, (u32)v << 16);
}
__device__ __forceinline__ fx4 mfma16(bfx8 a, bfx8 b, fx4 c) {
  return __builtin_amdgcn_mfma_f32_16x16x32_bf16(a, b, c, 0, 0, 0);
}
typedef __attribute__((address_space(1))) const unsigned int* as1p;
typedef __attribute__((address_space(3))) unsigned int* as3p;
__device__ __forceinline__ void gll16(const void* g, void* l) {
  __builtin_amdgcn_global_load_lds((as1p)g, (as3p)l, 16, 0, 0);
}
__device__ __forceinline__ void midbar_() { __builtin_amdgcn_s_barrier(); }
__device__ __forceinline__ void pend_() {
  __builtin_amdgcn_s_barrier();
  __builtin_amdgcn_sched_barrier(0);
}
#define SB0 __builtin_amdgcn_sched_barrier(0)
#define VMC4 do { asm volatile("s_waitcnt vmcnt(4)" ::: "memory"); SB0; } while (0)
#define VMC0 do { asm volatile("s_waitcnt vmcnt(0)" ::: "memory"); SB0; } while (0)

// ================= NEW core: register-pipelined 256x128 GEMM =================
// 8 waves (wr=wv>>1 in 0..3 -> A rows wr*64..+64; wc=wv&1 -> B rows wc*64..+64).
// LDS 96 KiB: A dbuf @0/@16384, B dbuf @32768/@40960 (u16 elems).
// Per tile, 4 phases of 8 MFMA; phase p issues ds_reads feeding phase p+1.
// One vmcnt(0)+s_barrier per tile at P2 (stage issued at P0); cross-tile
// reads for next P0 happen at P3 from the just-gated buffer.
template <bool SWAP, int NT, int LK>
__device__ __forceinline__ void gemm_rp(const u16* __restrict__ Ag,
                                        const u16* __restrict__ Bg,
                                        u16* lds, fx4 (&acc)[4][4],
                                        int wv, int lane) {
  const int l15 = lane & 15, kg = lane >> 4, l7 = lane & 7;
  const int wr = wv >> 1, wc = wv & 1;
  const int rs8 = lane >> 3, c8 = (lane & 7) * 8;
  constexpr int AS0 = 0, AS1 = 16384, BS0 = 32768, BS1 = 40960;
  bfx8 af[4][2], bf[4][2];

  auto stgA = [&](int t, int aoff) {
#pragma unroll
    for (int i = 0; i < 4; ++i)
      gll16(Ag + (size_t)(wv * 32 + i * 8 + rs8) * LK + t * 64 + c8,
            lds + aoff + (wv * 32 + i * 8) * 64);
  };
  auto stgB = [&](int t, int boff) {
#pragma unroll
    for (int i = 0; i < 2; ++i)
      gll16(Bg + (size_t)(wv * 16 + i * 8 + rs8) * LK + t * 64 + c8,
            lds + boff + (wv * 16 + i * 8) * 64);
  };
  auto RA = [&](int kk, int aoff) {
#pragma unroll
    for (int mt = 0; mt < 4; ++mt)
      af[mt][kk] = *(const bfx8*)(lds + aoff + (wr * 64 + mt * 16 + l15) * 64 +
                                  (((kk << 2) + kg) ^ l7) * 8);
  };
  auto RB = [&](int kk, int ng, int boff) {
#pragma unroll
    for (int q = 0; q < 2; ++q) {
      int nt = ng * 2 + q;
      bf[nt][kk] = *(const bfx8*)(lds + boff + (wc * 64 + nt * 16 + l15) * 64 +
                                  (((kk << 2) + kg) ^ l7) * 8);
    }
  };
  auto MM = [&](int kk, int ng) {
    __builtin_amdgcn_s_setprio(1);
#pragma unroll
    for (int mt = 0; mt < 4; ++mt)
#pragma unroll
      for (int q = 0; q < 2; ++q) {
        int nt = ng * 2 + q;
        if constexpr (SWAP)
          acc[mt][nt] = mfma16(bf[nt][kk], af[mt][kk], acc[mt][nt]);
        else
          acc[mt][nt] = mfma16(af[mt][kk], bf[nt][kk], acc[mt][nt]);
      }
    __builtin_amdgcn_s_setprio(0);
  };

  // prologue: tile 0 staged + gated; first-phase fragments read
  stgA(0, AS0); stgB(0, BS0);
  VMC0;
  __builtin_amdgcn_s_barrier();
  SB0;
  RA(0, AS0); RB(0, 0, BS0);

#pragma unroll 1
  for (int t = 0; t < NT - 1; ++t) {
    const int cA = (t & 1) ? AS1 : AS0, nA = (t & 1) ? AS0 : AS1;
    const int cB = (t & 1) ? BS1 : BS0, nB = (t & 1) ? BS0 : BS1;
    // P0: MFMA(kk0,nt01); stage t+1; reads for P1
    stgA(t + 1, nA); stgB(t + 1, nB);
    RB(0, 1, cB);
    MM(0, 0);
    SB0;
    // P1: MFMA(kk0,nt23); reads for P2
    RA(1, cA); RB(1, 0, cB);
    MM(0, 1);
    SB0;
    // P2: MFMA(kk1,nt01); reads for P3; gate tile t+1
    RB(1, 1, cB);
    MM(1, 0);
    VMC0;
    __builtin_amdgcn_s_barrier();
    SB0;
    // P3: MFMA(kk1,nt23); cross-tile reads for next P0 (gated buffer)
    RA(0, nA); RB(0, 0, nB);
    MM(1, 1);
    SB0;
  }
  { // tail tile (no stage, no gate, no cross-reads)
    constexpr int cAo = ((NT - 1) & 1) ? AS1 : AS0;
    constexpr int cBo = ((NT - 1) & 1) ? BS1 : BS0;
    RB(0, 1, cBo);
    MM(0, 0); SB0;
    RA(1, cAo); RB(1, 0, cBo);
    MM(0, 1); SB0;
    RB(1, 1, cBo);
    MM(1, 0); SB0;
    MM(1, 1); SB0;
  }
}

// ========== round-5 8-phase 256x256 core (kept for k_proj2) ==========
template <int NT, int LK>
__device__ __forceinline__ void gemm8(const u16* __restrict__ Ag,
                                      const u16* __restrict__ Bg,
                                      u16* lds, fx4 (&acc)[2][4][2][2],
                                      int wv, int lane) {
  const int l15 = lane & 15, kg = lane >> 4, l7 = lane & 7;
  const int wr = wv >> 2, wn = wv & 3;
  const int rsub = lane >> 3, csub = (lane & 7) * 8;
  constexpr int A0 = 0, A1 = 16384, B0 = 32768, B1 = 49152;
  bfx8 af[4][2], bf[2][2][2];

  auto stg = [&](const u16* g, int ldsoff, int tile, int half) {
    const u16* gp = g + (size_t)(half * 128 + wv * 16 + rsub) * LK + tile * 64 + csub;
    u16* lp = lds + ldsoff + half * 8192 + wv * 1024;
    gll16(gp, lp);
    gll16(gp + (size_t)8 * LK, lp + 512);
  };
  auto LA = [&](int boff, int mh) {
    const u16* base = lds + boff + mh * 8192 + wr * 4096;
#pragma unroll
    for (int mt = 0; mt < 4; ++mt)
#pragma unroll
      for (int kk = 0; kk < 2; ++kk)
        af[mt][kk] = *(const bfx8*)(base + (mt * 16 + l15) * 64 + (((kk << 2) + kg) ^ l7) * 8);
  };
  auto LB = [&](int boff, int nh) {
    const u16* base = lds + boff + nh * 8192 + wn * 2048;
#pragma unroll
    for (int nt = 0; nt < 2; ++nt)
#pragma unroll
      for (int kk = 0; kk < 2; ++kk)
        bf[nh][nt][kk] = *(const bfx8*)(base + (nt * 16 + l15) * 64 + (((kk << 2) + kg) ^ l7) * 8);
  };
  auto MM = [&](int mh, int nh) {
    __builtin_amdgcn_s_setprio(1);
#pragma unroll
    for (int mt = 0; mt < 4; ++mt)
#pragma unroll
      for (int nt = 0; nt < 2; ++nt)
#pragma unroll
        for (int kk = 0; kk < 2; ++kk)
          acc[mh][mt][nh][nt] = mfma16(af[mt][kk], bf[nh][nt][kk], acc[mh][mt][nh][nt]);
    __builtin_amdgcn_s_setprio(0);
  };

  stg(Ag, A0, 0, 0); stg(Ag, A0, 0, 1);
  stg(Bg, B0, 0, 0); stg(Bg, B0, 0, 1);
  stg(Ag, A1, 1, 0); stg(Bg, B1, 1, 1);
  VMC4;
  pend_();

  constexpr int NI = NT / 2;
#pragma unroll 1
  for (int i = 0; i < NI; ++i) {
    const int t = 2 * i;
    const bool more = (i + 1 < NI);
    LA(A0, 0); LB(B0, 0);
    stg(Ag, A1, t + 1, 1);
    midbar_(); MM(0, 0); pend_();
    LB(B0, 1);
    stg(Bg, B1, t + 1, 0);
    midbar_(); MM(0, 1); pend_();
    LA(A0, 1);
    if (more) stg(Ag, A0, t + 2, 0);
    midbar_(); MM(1, 1); pend_();
    if (more) stg(Bg, B0, t + 2, 1);
    midbar_(); MM(1, 0);
    if (more) { VMC4; } else { VMC0; }
    pend_();
    LA(A1, 0); LB(B1, 0);
    if (more) stg(Ag, A0, t + 2, 1);
    midbar_(); MM(0, 0); pend_();
    LB(B1, 1);
    if (more) stg(Bg, B0, t + 2, 0);
    midbar_(); MM(0, 1); pend_();
    LA(A1, 1);
    if (more) stg(Ag, A1, t + 3, 0);
    midbar_(); MM(1, 1); pend_();
    if (more) stg(Bg, B1, t + 3, 1);
    midbar_(); MM(1, 0);
    if (more) { VMC4; }
    pend_();
  }
}

// ---------------- W fp32 -> Wall bf16 swizzled ----------------
__global__ __launch_bounds__(256) void k_wconv(const float* __restrict__ Wk,
                                               const float* __restrict__ Wq,
                                               const float* __restrict__ Wv,
                                               u16* __restrict__ Wall) {
  int blk = blockIdx.x;          // 96 = 3 proj * 32
  int pr = blk >> 5;
  const float* src = (pr == 0) ? Wk : ((pr == 1) ? Wq : Wv);
  int oc = (blk & 31) * 8 + (threadIdx.x >> 5);
  int Cc = threadIdx.x & 31;
  const float4* s4 = (const float4*)(src + oc * 256 + Cc * 8);
  float4 a = s4[0], b = s4[1];
  alignas(16) u16 t[8] = {f2bf(a.x), f2bf(a.y), f2bf(a.z), f2bf(a.w),
                          f2bf(b.x), f2bf(b.y), f2bf(b.z), f2bf(b.w)};
  int o = pr * 256 + oc;
  int pos = (Cc & ~7) + ((Cc & 7) ^ (o & 7));
  *(uint4*)(Wall + o * 256 + pos * 8) = *(const uint4*)t;
}

// ---------------- x -> Xbf transpose/convert ----------------
__global__ __launch_bounds__(256) void k_xt(const float* __restrict__ x,
                                            u16* __restrict__ Xbf) {
  __shared__ u16 Xs[128 * 256];
  int b = blockIdx.x >> 7;
  int n0 = (blockIdx.x & 127) * 128;
  int tid = threadIdx.x;
  int ng = tid & 31, cgrp = tid >> 5;
  const float* xb = x + (size_t)b * 4194304 + n0 + ng * 4;
#pragma unroll
  for (int it = 0; it < 4; ++it) {
    int Cc = cgrp + it * 8;
    float4 v[8];
#pragma unroll
    for (int i = 0; i < 8; ++i)
      v[i] = *(const float4*)(xb + (size_t)(Cc * 8 + i) * 16384);
#pragma unroll
    for (int j = 0; j < 4; ++j) {
      int n = ng * 4 + j;
      alignas(16) u16 c8v[8];
#pragma unroll
      for (int i = 0; i < 8; ++i) c8v[i] = f2bf(((const float*)&v[i])[j]);
      int pos = (Cc & ~7) + ((Cc & 7) ^ (n & 7));
      *(uint4*)&Xs[n * 256 + pos * 8] = *(const uint4*)c8v;
    }
  }
  __syncthreads();
  u16* xo = Xbf + (size_t)b * 4194304 + (size_t)n0 * 256;
#pragma unroll
  for (int it = 0; it < 16; ++it) {
    int idx = tid + it * 256;
    int n = idx >> 5, chp = idx & 31;
    uint4 v = *(const uint4*)&Xs[n * 256 + chp * 8];
    *(uint4*)&xo[(size_t)n * 256 + chp * 8] = v;
  }
}

// ---------------- fused 3-projection GEMM (round-5 form) ----------------
__global__ __launch_bounds__(512) void k_proj2(const u16* __restrict__ Xbf,
                                               const u16* __restrict__ Wall,
                                               u16* __restrict__ Kb, u16* __restrict__ Qb,
                                               u16* __restrict__ Vb) {
  __shared__ u16 lds[65536];
  int bid = blockIdx.x;
  int vid = (bid & 7) * 192 + (bid >> 3);
  int nidx = vid / 3;
  int otile = vid - nidx * 3;
  int b = nidx >> 6, ntile = nidx & 63;
  int tid = threadIdx.x, lane = tid & 63, wv = tid >> 6;
  int l15 = lane & 15, kg = lane >> 4;
  int wr = wv >> 2, wn = wv & 3;
  const u16* Ag = Wall + otile * 65536;
  const u16* Bg = Xbf + (size_t)b * 4194304 + (size_t)ntile * 65536;
  fx4 acc[2][4][2][2];
#pragma unroll
  for (int mh = 0; mh < 2; ++mh)
#pragma unroll
    for (int mt = 0; mt < 4; ++mt)
#pragma unroll
      for (int nh = 0; nh < 2; ++nh)
#pragma unroll
        for (int nt = 0; nt < 2; ++nt) acc[mh][mt][nh][nt] = (fx4)0.0f;

  gemm8<4, 256>(Ag, Bg, lds, acc, wv, lane);

  u16* dst = (otile == 0) ? Kb : ((otile == 1) ? Qb : Vb);
#pragma unroll
  for (int mh = 0; mh < 2; ++mh)
#pragma unroll
    for (int mt = 0; mt < 4; ++mt) {
      int o = mh * 128 + wr * 64 + mt * 16 + kg * 4;
      int h = o >> 5;
      size_t bhro = (size_t)(b * 8 + h) * 524288;
#pragma unroll
      for (int nh = 0; nh < 2; ++nh)
#pragma unroll
        for (int nt = 0; nt < 2; ++nt) {
          int p = ntile * 16 + nh * 8 + wn * 2 + nt;
          size_t ro = bhro + (size_t)p * 512;
          int p7 = p & 7;
#pragma unroll
          for (int j = 0; j < 4; ++j) {
            int f = ((o & 31) + j) * 16 + l15;
            int ch = (f >> 3) ^ p7;
            dst[ro + ch * 8 + (f & 7)] = f2bf(acc[mh][mt][nh][nt][j]);
          }
        }
    }
}

// ---------------- E-GEMM + exp2 -> Pt, fused partial Z ----------------
// grid 2048 (64 bh x 4 qt x 8 pt), 512 thr, 256(q) x 128(p), NT=8.
// SWAP: C row = p (kg*4+j), col = q (l15).
__global__ __launch_bounds__(512) void k_egemm(const u16* __restrict__ Qb,
                                               const u16* __restrict__ Kb,
                                               u16* __restrict__ Pt,
                                               float* __restrict__ Zpart) {
  __shared__ u16 lds[49152];
  int bid = blockIdx.x;
  int vid = (bid & 7) * 256 + (bid >> 3);
  int bh = vid >> 5, qt = (vid >> 3) & 3, pt = vid & 7;
  int q0 = qt * 256, p0 = pt * 128;
  int tid = threadIdx.x, lane = tid & 63, wv = tid >> 6;
  int l15 = lane & 15, kg = lane >> 4, l7 = lane & 7;
  int wr = wv >> 1, wc = wv & 1;
  const u16* Ag = Qb + (size_t)bh * 524288 + (size_t)q0 * 512;
  const u16* Bg = Kb + (size_t)bh * 524288 + (size_t)p0 * 512;
  fx4 acc[4][4];
#pragma unroll
  for (int mt = 0; mt < 4; ++mt)
#pragma unroll
    for (int nt = 0; nt < 4; ++nt) acc[mt][nt] = (fx4)0.0f;

  gemm_rp<true, 8, 512>(Ag, Bg, lds, acc, wv, lane);

  size_t pbase = (size_t)bh * 1048576;
  float zac[4][4];
#pragma unroll
  for (int nt = 0; nt < 4; ++nt)
#pragma unroll
    for (int j = 0; j < 4; ++j) zac[nt][j] = 0.f;
#pragma unroll
  for (int mt = 0; mt < 4; ++mt) {
    int q = q0 + wr * 64 + mt * 16 + l15;
    size_t qrow = pbase + (size_t)q * 1024;
#pragma unroll
    for (int nt = 0; nt < 4; ++nt) {
      int p4 = p0 + wc * 64 + nt * 16 + kg * 4;
      alignas(8) u16 e4[4];
#pragma unroll
      for (int j = 0; j < 4; ++j) {
        float e = exp2f(acc[mt][nt][j] * KC1);
        zac[nt][j] += e;
        e4[j] = f2bf(e);
      }
      int ch = (p4 >> 3) ^ l7;
      *(u64*)(Pt + qrow + ch * 8 + (p4 & 7)) = *(const u64*)e4;
    }
  }
  // reduce z over the 16 q-lanes (l15)
#pragma unroll
  for (int nt = 0; nt < 4; ++nt)
#pragma unroll
    for (int j = 0; j < 4; ++j) {
      float v = zac[nt][j];
      v += __shfl_xor(v, 1);
      v += __shfl_xor(v, 2);
      v += __shfl_xor(v, 4);
      v += __shfl_xor(v, 8);
      zac[nt][j] = v;
    }
  if (l15 == 0) {
    size_t zb = (size_t)(qt * 4 + wr) * 65536 + (size_t)bh * 1024;
#pragma unroll
    for (int nt = 0; nt < 4; ++nt) {
      int p4 = p0 + wc * 64 + nt * 16 + kg * 4;
      float4 zv;
      zv.x = zac[nt][0]; zv.y = zac[nt][1];
      zv.z = zac[nt][2]; zv.w = zac[nt][3];
      *(float4*)&Zpart[zb + p4] = zv;
    }
  }
}

__global__ __launch_bounds__(256) void k_zfinal(const float* __restrict__ Zpart,
                                                float* __restrict__ RZ) {
  int idx = blockIdx.x * 256 + threadIdx.x; // 65536
  float s = 0.f;
#pragma unroll
  for (int k = 0; k < 16; ++k) s += Zpart[(size_t)k * 65536 + idx];
  RZ[idx] = 1.0f / s;
}

// ---------------- Vb [p][f] -> Vt [f][p] with 1/Z scale ----------------
__global__ __launch_bounds__(256) void k_vt(const u16* __restrict__ Vb,
                                            const float* __restrict__ RZ,
                                            u16* __restrict__ Vt) {
  __shared__ u16 Vl[64 * 512];
  int bh = blockIdx.x >> 4;
  int ptile = blockIdx.x & 15;
  int tid = threadIdx.x;
  const u16* src = Vb + (size_t)bh * 524288 + (size_t)ptile * 32768;
#pragma unroll
  for (int it = 0; it < 16; ++it) {
    int idx = tid + it * 256;
    int pl = idx >> 6, g = idx & 63;
    float rz = RZ[bh * 1024 + ptile * 64 + pl];
    uint4 v = *(const uint4*)&src[(size_t)pl * 512 + g * 8];
    int cf = g ^ (pl & 7);
    u32 w[4] = {v.x, v.y, v.z, v.w};
    alignas(16) u16 c8v[8];
#pragma unroll
    for (int i = 0; i < 4; ++i) {
      c8v[2 * i]     = f2bf(bf2f((u16)w[i]) * rz);
      c8v[2 * i + 1] = f2bf(bf2f((u16)(w[i] >> 16)) * rz);
    }
    *(uint4*)&Vl[pl * 512 + cf * 8] = *(const uint4*)c8v;
  }
  __syncthreads();
  u16* dst = Vt + (size_t)bh * 524288;
#pragma unroll
  for (int it = 0; it < 16; ++it) {
    int f = (tid & 63) + (it & 7) * 64;
    int pc = (tid >> 6) * 2 + (it >> 3);
    int base = pc * 8 * 512 + f;
    u32 x0 = (u32)Vl[base] | ((u32)Vl[base + 512] << 16);
    u32 x1 = (u32)Vl[base + 1024] | ((u32)Vl[base + 1536] << 16);
    u32 x2 = (u32)Vl[base + 2048] | ((u32)Vl[base + 2560] << 16);
    u32 x3 = (u32)Vl[base + 3072] | ((u32)Vl[base + 3584] << 16);
    uint4 pk; pk.x = x0; pk.y = x1; pk.z = x2; pk.w = x3;
    int col = ptile * 8 + (pc ^ (f & 7));
    *(uint4*)&dst[(size_t)f * 1024 + col * 8] = pk;
  }
}

// ---------------- PV-GEMM -> out ----------------
// grid 1024 (64 bh x 4 qt x 4 ft), 512 thr, 256(q) x 128(f), NT=16.
__global__ __launch_bounds__(512) void k_pv(const u16* __restrict__ Pt,
                                            const u16* __restrict__ Vt,
                                            float* __restrict__ out) {
  __shared__ u16 lds[49152];
  int bid = blockIdx.x;
  int vid = (bid & 7) * 128 + (bid >> 3);
  int bh = vid >> 4, qt = (vid >> 2) & 3, ft = vid & 3;
  int q0 = qt * 256, f0 = ft * 128;
  int tid = threadIdx.x, lane = tid & 63, wv = tid >> 6;
  int l15 = lane & 15, kg = lane >> 4;
  int wr = wv >> 1, wc = wv & 1;
  const u16* Ag = Pt + (size_t)bh * 1048576 + (size_t)q0 * 1024;
  const u16* Bg = Vt + (size_t)bh * 524288 + (size_t)f0 * 1024;
  fx4 acc[4][4];
#pragma unroll
  for (int mt = 0; mt < 4; ++mt)
#pragma unroll
    for (int nt = 0; nt < 4; ++nt) acc[mt][nt] = (fx4)0.0f;

  gemm_rp<false, 16, 1024>(Ag, Bg, lds, acc, wv, lane);

#pragma unroll
  for (int mt = 0; mt < 4; ++mt) {
    int qb_ = q0 + wr * 64 + mt * 16 + kg * 4;
#pragma unroll
    for (int nt = 0; nt < 4; ++nt) {
      int f = f0 + wc * 64 + nt * 16 + l15;
      int d = f >> 4, t = f & 15;
      size_t cb = (size_t)(bh * 32 + d) * 16384 + t;
#pragma unroll
      for (int j = 0; j < 4; ++j)
        out[cb + (size_t)(qb_ + j) * 16] = acc[mt][nt][j];
    }
  }
}

extern "C" void kernel_launch(void* const* d_in, const int* in_sizes, int n_in,
                              void* d_out, int out_size, void* d_ws, size_t ws_size,
                              hipStream_t stream) {
  (void)in_sizes; (void)n_in; (void)out_size; (void)ws_size;
  const float* x  = (const float*)d_in[0];
  const float* Wk = (const float*)d_in[1];
  const float* Wq = (const float*)d_in[2];
  const float* Wv = (const float*)d_in[3];
  float* out = (float*)d_out;

  u16* Kb  = (u16*)d_ws;                  // [ 0, 64) MiB  [64 bh][1024 p][512 f]
  u16* Qb  = Kb + 33554432;               // [64,128) MiB
  u16* Vb  = Qb + 33554432;               // [128,192) MiB
  u16* Xbf = Vb + 33554432;               // [192,256) MiB [8 b][16384 n][256 c]
  u16* Pt  = Xbf;                         // [192,320) MiB (overlays dead Xbf)
  u16* Vt  = Qb;                          // [64,128) MiB  (overlays dead Qb)
  float* Zpart = (float*)(Kb + 167772160);// 320 MiB: [16][64][1024]
  float* RZ = Zpart + 1048576;            // [64][1024]
  u16* Wall = (u16*)(RZ + 65536);         // [768][256]

  k_wconv<<<96, 256, 0, stream>>>(Wk, Wq, Wv, Wall);
  k_xt<<<1024, 256, 0, stream>>>(x, Xbf);
  k_proj2<<<1536, 512, 0, stream>>>(Xbf, Wall, Kb, Qb, Vb);
  k_egemm<<<2048, 512, 0, stream>>>(Qb, Kb, Pt, Zpart);
  k_zfinal<<<256, 256, 0, stream>>>(Zpart, RZ);
  k_vt<<<1024, 256, 0, stream>>>(Vb, RZ, Vt);
  k_pv<<<1024, 512, 0, stream>>>(Pt, Vt, out);
}

// Round 8
// 361.162 us; speedup vs baseline: 1.2257x; 1.1934x over previous
//
#include <hip/hip_runtime.h>

// MultiHeadAttention: B=8, C=256, H=8, D=32, T=16, P=1024, F=D*T=512
//  k_wconv : W fp32 -> Wall[768][256] bf16 (chunk-swizzled by o&7)
//  k_xt    : x fp32 [b][c][n] -> Xbf [b][n][c] bf16 (chunk-swizzled by n&7)
//  k_proj2 : GEMM Wall x Xbf -> Kb,Qb,Vb [bh][p][512] bf16 (swizzled)
//  k_egemm : Pt[bh][q][p] = bf16(exp2(QK^T/S)) + fused partial Z (8 slices)
//            SWAPPED operands -> C rows=p -> 8B Pt stores, Z via shfl
//  k_zfinal: RZ[bh][p] = 1/sum(8 Zpart slices)
//  k_vt    : Vb [p][f] -> Vt [bh][f][1024] bf16 with 1/Z[p] folded in
//  k_pv    : out = Pt x Vt' -> d_out fp32
// GEMM core (gemm1g): 256x256 tile, 8 waves, ONE gate per K-tile.
// Fragments read one phase ahead of their MFMA (register pipeline):
//   ph1: LA1      | MM(0,0)          ph2: LB1        | MM(1,0)
//   GATE: lgkmcnt(0) + vmcnt(0) + s_barrier   (retires stage(t+1), frees cur)
//   ph3: LB0'next + stageA(t+2->cur) | MM(0,1)
//   ph4: LA0'next + stageB(t+2->cur) | MM(1,1)
// Compiler's fine-grained lgkmcnt interleaves reads with the MFMA clusters.

typedef unsigned short u16;
typedef unsigned int u32;
typedef unsigned long long u64;
typedef __attribute__((ext_vector_type(8))) short bfx8;
typedef __attribute__((ext_vector_type(4))) float fx4;

constexpr float KC1 = 1.4426950408889634f / 22.627416997969522f; // log2(e)/sqrt(512)

__device__ __forceinline__ u16 f2bf(float f) {
  u32 u = __builtin_bit_cast(u32, f);
  return (u16)((u + 0x7fffu + ((u >> 16) & 1u)) >> 16);
}
__device__ __forceinline__ float bf2f(u16 v) {
  return __builtin_bit_cast(float, (u32)v << 16);
}
__device__ __forceinline__ fx4 mfma16(bfx8 a, bfx8 b, fx4 c) {
  return __builtin_amdgcn_mfma_f32_16x16x32_bf16(a, b, c, 0, 0, 0);
}
typedef __attribute__((address_space(1))) const unsigned int* as1p;
typedef __attribute__((address_space(3))) unsigned int* as3p;
__device__ __forceinline__ void gll16(const void* g, void* l) {
  __builtin_amdgcn_global_load_lds((as1p)g, (as3p)l, 16, 0, 0);
}
#define SB0 __builtin_amdgcn_sched_barrier(0)

// ---- one-gate register-pipelined 256x256 GEMM core, NT K-tiles of 64 ----
// LDS 128 KiB: A dbuf @0/@16384, B dbuf @32768/@49152 (u16 offsets).
// acc[mh][mt][nh][nt]: (non-swap) row = mh*128+wr*64+mt*16+kg*4+j,
//                      col = nh*128+wn*32+nt*16+l15.  SWAP: row/col sides trade.
template <bool SWAP, int NT, int LK>
__device__ __forceinline__ void gemm1g(const u16* __restrict__ Ag,
                                       const u16* __restrict__ Bg,
                                       u16* lds, fx4 (&acc)[2][4][2][2],
                                       int wv, int lane) {
  const int l15 = lane & 15, kg = lane >> 4, l7 = lane & 7;
  const int wr = wv >> 2, wn = wv & 3;
  const int rsub = lane >> 3, csub = (lane & 7) * 8;
  constexpr int A0 = 0, A1 = 16384, B0 = 32768, B1 = 49152;
  bfx8 af[2][4][2];   // [mh][mt][kk]
  bfx8 bf[2][2][2];   // [nh][nt][kk]

  auto stg = [&](const u16* g, int ldsoff, int tile, int half) {
    const u16* gp = g + (size_t)(half * 128 + wv * 16 + rsub) * LK + tile * 64 + csub;
    u16* lp = lds + ldsoff + half * 8192 + wv * 1024;
    gll16(gp, lp);
    gll16(gp + (size_t)8 * LK, lp + 512);
  };
  auto stgA = [&](int t, int buf) {   // 4 gll16: both A halves of tile t
    int aoff = buf ? A1 : A0;
    stg(Ag, aoff, t, 0); stg(Ag, aoff, t, 1);
  };
  auto stgB = [&](int t, int buf) {   // 4 gll16
    int boff = buf ? B1 : B0;
    stg(Bg, boff, t, 0); stg(Bg, boff, t, 1);
  };
  auto LA = [&](int boff, int mh) {   // 8 ds_read_b128 into af[mh]
    const u16* base = lds + boff + mh * 8192 + wr * 4096;
#pragma unroll
    for (int mt = 0; mt < 4; ++mt)
#pragma unroll
      for (int kk = 0; kk < 2; ++kk)
        af[mh][mt][kk] = *(const bfx8*)(base + (mt * 16 + l15) * 64 + (((kk << 2) + kg) ^ l7) * 8);
  };
  auto LB = [&](int boff, int nh) {   // 4 ds_read_b128 into bf[nh]
    const u16* base = lds + boff + nh * 8192 + wn * 2048;
#pragma unroll
    for (int nt = 0; nt < 2; ++nt)
#pragma unroll
      for (int kk = 0; kk < 2; ++kk)
        bf[nh][nt][kk] = *(const bfx8*)(base + (nt * 16 + l15) * 64 + (((kk << 2) + kg) ^ l7) * 8);
  };
  auto MM = [&](int mh, int nh) {
    __builtin_amdgcn_s_setprio(1);
#pragma unroll
    for (int mt = 0; mt < 4; ++mt)
#pragma unroll
      for (int nt = 0; nt < 2; ++nt)
#pragma unroll
        for (int kk = 0; kk < 2; ++kk)
          if constexpr (SWAP)
            acc[mh][mt][nh][nt] = mfma16(bf[nh][nt][kk], af[mh][mt][kk], acc[mh][mt][nh][nt]);
          else
            acc[mh][mt][nh][nt] = mfma16(af[mh][mt][kk], bf[nh][nt][kk], acc[mh][mt][nh][nt]);
    __builtin_amdgcn_s_setprio(0);
  };

  // prologue: stage tiles 0 (buf0) and 1 (buf1); wait tile 0 only.
  stgA(0, 0); stgB(0, 0);
  stgA(1, 1); stgB(1, 1);
  asm volatile("s_waitcnt vmcnt(8)" ::: "memory");
  __builtin_amdgcn_s_barrier();
  SB0;
  LA(A0, 0);            // preload af0, bf0 of tile 0
  LB(B0, 0);

#pragma unroll 1
  for (int t = 0; t < NT - 1; ++t) {
    const int cur = t & 1, nxt = cur ^ 1;
    const int cA = cur ? A1 : A0, cB = cur ? B1 : B0;
    const int nA = cur ? A0 : A1, nB = cur ? B0 : B1;
    // ph1: af1 of cur | MM(0,0) = af0*bf0
    LA(cA, 1);
    MM(0, 0);
    // ph2: bf1 of cur | MM(1,0) = af1*bf0
    LB(cB, 1);
    MM(1, 0);
    // GATE: all cur-buf reads landed; stage(t+1) retired; cur buf writable
    asm volatile("s_waitcnt lgkmcnt(0)" ::: "memory");
    asm volatile("s_waitcnt vmcnt(0)" ::: "memory");
    __builtin_amdgcn_s_barrier();
    SB0;
    // ph3: bf0' of next tile | stage A(t+2) into cur | MM(0,1) = af0*bf1
    LB(nB, 0);
    if (t + 2 < NT) stgA(t + 2, cur);
    MM(0, 1);
    // ph4: af0' of next tile | stage B(t+2) into cur | MM(1,1) = af1*bf1
    LA(nA, 0);
    if (t + 2 < NT) stgB(t + 2, cur);
    MM(1, 1);
  }
  { // tail tile NT-1 (data gated at gate(NT-2); no stages, no cross-reads)
    constexpr int cur = (NT - 1) & 1;
    constexpr int cA = cur ? A1 : A0, cB = cur ? B1 : B0;
    LA(cA, 1);
    MM(0, 0);
    LB(cB, 1);
    MM(1, 0);
    MM(0, 1);
    MM(1, 1);
  }
}

// ---------------- W fp32 -> Wall bf16 swizzled ----------------
__global__ __launch_bounds__(256) void k_wconv(const float* __restrict__ Wk,
                                               const float* __restrict__ Wq,
                                               const float* __restrict__ Wv,
                                               u16* __restrict__ Wall) {
  int blk = blockIdx.x;          // 96 = 3 proj * 32
  int pr = blk >> 5;
  const float* src = (pr == 0) ? Wk : ((pr == 1) ? Wq : Wv);
  int oc = (blk & 31) * 8 + (threadIdx.x >> 5);
  int Cc = threadIdx.x & 31;
  const float4* s4 = (const float4*)(src + oc * 256 + Cc * 8);
  float4 a = s4[0], b = s4[1];
  alignas(16) u16 t[8] = {f2bf(a.x), f2bf(a.y), f2bf(a.z), f2bf(a.w),
                          f2bf(b.x), f2bf(b.y), f2bf(b.z), f2bf(b.w)};
  int o = pr * 256 + oc;
  int pos = (Cc & ~7) + ((Cc & 7) ^ (o & 7));
  *(uint4*)(Wall + o * 256 + pos * 8) = *(const uint4*)t;
}

// ---------------- x -> Xbf transpose/convert ----------------
__global__ __launch_bounds__(256) void k_xt(const float* __restrict__ x,
                                            u16* __restrict__ Xbf) {
  __shared__ u16 Xs[128 * 256];
  int b = blockIdx.x >> 7;
  int n0 = (blockIdx.x & 127) * 128;
  int tid = threadIdx.x;
  int ng = tid & 31, cgrp = tid >> 5;
  const float* xb = x + (size_t)b * 4194304 + n0 + ng * 4;
#pragma unroll
  for (int it = 0; it < 4; ++it) {
    int Cc = cgrp + it * 8;
    float4 v[8];
#pragma unroll
    for (int i = 0; i < 8; ++i)
      v[i] = *(const float4*)(xb + (size_t)(Cc * 8 + i) * 16384);
#pragma unroll
    for (int j = 0; j < 4; ++j) {
      int n = ng * 4 + j;
      alignas(16) u16 c8v[8];
#pragma unroll
      for (int i = 0; i < 8; ++i) c8v[i] = f2bf(((const float*)&v[i])[j]);
      int pos = (Cc & ~7) + ((Cc & 7) ^ (n & 7));
      *(uint4*)&Xs[n * 256 + pos * 8] = *(const uint4*)c8v;
    }
  }
  __syncthreads();
  u16* xo = Xbf + (size_t)b * 4194304 + (size_t)n0 * 256;
#pragma unroll
  for (int it = 0; it < 16; ++it) {
    int idx = tid + it * 256;
    int n = idx >> 5, chp = idx & 31;
    uint4 v = *(const uint4*)&Xs[n * 256 + chp * 8];
    *(uint4*)&xo[(size_t)n * 256 + chp * 8] = v;
  }
}

// ---------------- fused 3-projection GEMM ----------------
// grid 1536 (=512 n-groups x 3 otiles), 512 thr, 256(o) x 256(n), NT=4.
__global__ __launch_bounds__(512) void k_proj2(const u16* __restrict__ Xbf,
                                               const u16* __restrict__ Wall,
                                               u16* __restrict__ Kb, u16* __restrict__ Qb,
                                               u16* __restrict__ Vb) {
  __shared__ u16 lds[65536];
  int bid = blockIdx.x;
  int vid = (bid & 7) * 192 + (bid >> 3);
  int nidx = vid / 3;
  int otile = vid - nidx * 3;
  int b = nidx >> 6, ntile = nidx & 63;
  int tid = threadIdx.x, lane = tid & 63, wv = tid >> 6;
  int l15 = lane & 15, kg = lane >> 4;
  int wr = wv >> 2, wn = wv & 3;
  const u16* Ag = Wall + otile * 65536;
  const u16* Bg = Xbf + (size_t)b * 4194304 + (size_t)ntile * 65536;
  fx4 acc[2][4][2][2];
#pragma unroll
  for (int mh = 0; mh < 2; ++mh)
#pragma unroll
    for (int mt = 0; mt < 4; ++mt)
#pragma unroll
      for (int nh = 0; nh < 2; ++nh)
#pragma unroll
        for (int nt = 0; nt < 2; ++nt) acc[mh][mt][nh][nt] = (fx4)0.0f;

  gemm1g<false, 4, 256>(Ag, Bg, lds, acc, wv, lane);

  u16* dst = (otile == 0) ? Kb : ((otile == 1) ? Qb : Vb);
#pragma unroll
  for (int mh = 0; mh < 2; ++mh)
#pragma unroll
    for (int mt = 0; mt < 4; ++mt) {
      int o = mh * 128 + wr * 64 + mt * 16 + kg * 4;
      int h = o >> 5;
      size_t bhro = (size_t)(b * 8 + h) * 524288;
#pragma unroll
      for (int nh = 0; nh < 2; ++nh)
#pragma unroll
        for (int nt = 0; nt < 2; ++nt) {
          int p = ntile * 16 + nh * 8 + wn * 2 + nt;
          size_t ro = bhro + (size_t)p * 512;
          int p7 = p & 7;
#pragma unroll
          for (int j = 0; j < 4; ++j) {
            int f = ((o & 31) + j) * 16 + l15;
            int ch = (f >> 3) ^ p7;
            dst[ro + ch * 8 + (f & 7)] = f2bf(acc[mh][mt][nh][nt][j]);
          }
        }
    }
}

// ---------------- E-GEMM + exp2 -> Pt, fused partial Z ----------------
// grid 1024 (bh x 4 qt x 4 pt), 512 thr, 256x256, NT=8. SWAP:
// row = p = p0+nh*128+wn*32+nt*16+kg*4+j, col = q = q0+mh*128+wr*64+mt*16+l15.
__global__ __launch_bounds__(512) void k_egemm(const u16* __restrict__ Qb,
                                               const u16* __restrict__ Kb,
                                               u16* __restrict__ Pt,
                                               float* __restrict__ Zpart) {
  __shared__ u16 lds[65536];
  int bid = blockIdx.x;
  int vid = (bid & 7) * 128 + (bid >> 3);
  int bh = vid >> 4, qt = (vid >> 2) & 3, pt = vid & 3;
  int q0 = qt * 256, p0 = pt * 256;
  int tid = threadIdx.x, lane = tid & 63, wv = tid >> 6;
  int l15 = lane & 15, kg = lane >> 4;
  int wr = wv >> 2, wn = wv & 3;
  const u16* Ag = Qb + (size_t)bh * 524288 + (size_t)q0 * 512;
  const u16* Bg = Kb + (size_t)bh * 524288 + (size_t)p0 * 512;
  fx4 acc[2][4][2][2];
#pragma unroll
  for (int mh = 0; mh < 2; ++mh)
#pragma unroll
    for (int mt = 0; mt < 4; ++mt)
#pragma unroll
      for (int nh = 0; nh < 2; ++nh)
#pragma unroll
        for (int nt = 0; nt < 2; ++nt) acc[mh][mt][nh][nt] = (fx4)0.0f;

  gemm1g<true, 8, 512>(Ag, Bg, lds, acc, wv, lane);

  size_t pbase = (size_t)bh * 1048576;
  float zac[2][2][4];
#pragma unroll
  for (int nh = 0; nh < 2; ++nh)
#pragma unroll
    for (int nt = 0; nt < 2; ++nt)
#pragma unroll
      for (int j = 0; j < 4; ++j) zac[nh][nt][j] = 0.f;
#pragma unroll
  for (int mh = 0; mh < 2; ++mh)
#pragma unroll
    for (int mt = 0; mt < 4; ++mt) {
      int q = q0 + mh * 128 + wr * 64 + mt * 16 + l15;
      size_t qrow = pbase + (size_t)q * 1024;
      int q7 = l15 & 7;
#pragma unroll
      for (int nh = 0; nh < 2; ++nh)
#pragma unroll
        for (int nt = 0; nt < 2; ++nt) {
          int p4 = p0 + nh * 128 + wn * 32 + nt * 16 + kg * 4;
          alignas(8) u16 e4[4];
#pragma unroll
          for (int j = 0; j < 4; ++j) {
            float e = exp2f(acc[mh][mt][nh][nt][j] * KC1);
            zac[nh][nt][j] += e;
            e4[j] = f2bf(e);
          }
          int ch = (p4 >> 3) ^ q7;
          *(u64*)(Pt + qrow + ch * 8 + (p4 & 7)) = *(const u64*)e4;
        }
    }
  // reduce z over the 16 q-lanes (l15)
#pragma unroll
  for (int nh = 0; nh < 2; ++nh)
#pragma unroll
    for (int nt = 0; nt < 2; ++nt)
#pragma unroll
      for (int j = 0; j < 4; ++j) {
        float v = zac[nh][nt][j];
        v += __shfl_xor(v, 1);
        v += __shfl_xor(v, 2);
        v += __shfl_xor(v, 4);
        v += __shfl_xor(v, 8);
        zac[nh][nt][j] = v;
      }
  if (l15 == 0) {
    size_t zb = (size_t)(qt * 2 + wr) * 65536 + (size_t)bh * 1024;
#pragma unroll
    for (int nh = 0; nh < 2; ++nh)
#pragma unroll
      for (int nt = 0; nt < 2; ++nt) {
        int p4 = p0 + nh * 128 + wn * 32 + nt * 16 + kg * 4;
        float4 zv;
        zv.x = zac[nh][nt][0]; zv.y = zac[nh][nt][1];
        zv.z = zac[nh][nt][2]; zv.w = zac[nh][nt][3];
        *(float4*)&Zpart[zb + p4] = zv;
      }
  }
}

__global__ __launch_bounds__(256) void k_zfinal(const float* __restrict__ Zpart,
                                                float* __restrict__ RZ) {
  int idx = blockIdx.x * 256 + threadIdx.x; // 65536
  float s = 0.f;
#pragma unroll
  for (int k = 0; k < 8; ++k) s += Zpart[(size_t)k * 65536 + idx];
  RZ[idx] = 1.0f / s;
}

// ---------------- Vb [p][f] -> Vt [f][p] with 1/Z scale ----------------
__global__ __launch_bounds__(256) void k_vt(const u16* __restrict__ Vb,
                                            const float* __restrict__ RZ,
                                            u16* __restrict__ Vt) {
  __shared__ u16 Vl[64 * 512];
  int bh = blockIdx.x >> 4;
  int ptile = blockIdx.x & 15;
  int tid = threadIdx.x;
  const u16* src = Vb + (size_t)bh * 524288 + (size_t)ptile * 32768;
#pragma unroll
  for (int it = 0; it < 16; ++it) {
    int idx = tid + it * 256;
    int pl = idx >> 6, g = idx & 63;
    float rz = RZ[bh * 1024 + ptile * 64 + pl];
    uint4 v = *(const uint4*)&src[(size_t)pl * 512 + g * 8];
    int cf = g ^ (pl & 7);
    u32 w[4] = {v.x, v.y, v.z, v.w};
    alignas(16) u16 c8v[8];
#pragma unroll
    for (int i = 0; i < 4; ++i) {
      c8v[2 * i]     = f2bf(bf2f((u16)w[i]) * rz);
      c8v[2 * i + 1] = f2bf(bf2f((u16)(w[i] >> 16)) * rz);
    }
    *(uint4*)&Vl[pl * 512 + cf * 8] = *(const uint4*)c8v;
  }
  __syncthreads();
  u16* dst = Vt + (size_t)bh * 524288;
#pragma unroll
  for (int it = 0; it < 16; ++it) {
    int f = (tid & 63) + (it & 7) * 64;
    int pc = (tid >> 6) * 2 + (it >> 3);
    int base = pc * 8 * 512 + f;
    u32 x0 = (u32)Vl[base] | ((u32)Vl[base + 512] << 16);
    u32 x1 = (u32)Vl[base + 1024] | ((u32)Vl[base + 1536] << 16);
    u32 x2 = (u32)Vl[base + 2048] | ((u32)Vl[base + 2560] << 16);
    u32 x3 = (u32)Vl[base + 3072] | ((u32)Vl[base + 3584] << 16);
    uint4 pk; pk.x = x0; pk.y = x1; pk.z = x2; pk.w = x3;
    int col = ptile * 8 + (pc ^ (f & 7));
    *(uint4*)&dst[(size_t)f * 1024 + col * 8] = pk;
  }
}

// ---------------- PV-GEMM -> out ----------------
// grid 512 (bh x 8 tiles), 512 thr, 256x256, NT=16.
__global__ __launch_bounds__(512) void k_pv(const u16* __restrict__ Pt,
                                            const u16* __restrict__ Vt,
                                            float* __restrict__ out) {
  __shared__ u16 lds[65536];
  int bid = blockIdx.x;
  int vid = (bid & 7) * 64 + (bid >> 3);
  int bh = vid >> 3, tile = vid & 7;
  int q0 = (tile >> 1) * 256, f0 = (tile & 1) * 256;
  int tid = threadIdx.x, lane = tid & 63, wv = tid >> 6;
  int l15 = lane & 15, kg = lane >> 4;
  int wr = wv >> 2, wn = wv & 3;
  const u16* Ag = Pt + (size_t)bh * 1048576 + (size_t)q0 * 1024;
  const u16* Bg = Vt + (size_t)bh * 524288 + (size_t)f0 * 1024;
  fx4 acc[2][4][2][2];
#pragma unroll
  for (int mh = 0; mh < 2; ++mh)
#pragma unroll
    for (int mt = 0; mt < 4; ++mt)
#pragma unroll
      for (int nh = 0; nh < 2; ++nh)
#pragma unroll
        for (int nt = 0; nt < 2; ++nt) acc[mh][mt][nh][nt] = (fx4)0.0f;

  gemm1g<false, 16, 1024>(Ag, Bg, lds, acc, wv, lane);

#pragma unroll
  for (int mh = 0; mh < 2; ++mh)
#pragma unroll
    for (int mt = 0; mt < 4; ++mt) {
      int qb_ = q0 + mh * 128 + wr * 64 + mt * 16 + kg * 4;
#pragma unroll
      for (int nh = 0; nh < 2; ++nh)
#pragma unroll
        for (int nt = 0; nt < 2; ++nt) {
          int f = f0 + nh * 128 + wn * 32 + nt * 16 + l15;
          int d = f >> 4, t = f & 15;
          size_t cb = (size_t)(bh * 32 + d) * 16384 + t;
#pragma unroll
          for (int j = 0; j < 4; ++j)
            out[cb + (size_t)(qb_ + j) * 16] = acc[mh][mt][nh][nt][j];
        }
    }
}

extern "C" void kernel_launch(void* const* d_in, const int* in_sizes, int n_in,
                              void* d_out, int out_size, void* d_ws, size_t ws_size,
                              hipStream_t stream) {
  (void)in_sizes; (void)n_in; (void)out_size; (void)ws_size;
  const float* x  = (const float*)d_in[0];
  const float* Wk = (const float*)d_in[1];
  const float* Wq = (const float*)d_in[2];
  const float* Wv = (const float*)d_in[3];
  float* out = (float*)d_out;

  u16* Kb  = (u16*)d_ws;                  // [ 0, 64) MiB  [64 bh][1024 p][512 f]
  u16* Qb  = Kb + 33554432;               // [64,128) MiB
  u16* Vb  = Qb + 33554432;               // [128,192) MiB
  u16* Xbf = Vb + 33554432;               // [192,256) MiB [8 b][16384 n][256 c]
  u16* Pt  = Xbf;                         // [192,320) MiB (overlays dead Xbf)
  u16* Vt  = Qb;                          // [64,128) MiB  (overlays dead Qb)
  float* Zpart = (float*)(Kb + 167772160);// 320 MiB: [8][64][1024]
  float* RZ = Zpart + 524288;             // [64][1024]
  u16* Wall = (u16*)(RZ + 65536);         // [768][256]

  k_wconv<<<96, 256, 0, stream>>>(Wk, Wq, Wv, Wall);
  k_xt<<<1024, 256, 0, stream>>>(x, Xbf);
  k_proj2<<<1536, 512, 0, stream>>>(Xbf, Wall, Kb, Qb, Vb);
  k_egemm<<<1024, 512, 0, stream>>>(Qb, Kb, Pt, Zpart);
  k_zfinal<<<256, 256, 0, stream>>>(Zpart, RZ);
  k_vt<<<1024, 256, 0, stream>>>(Vb, RZ, Vt);
  k_pv<<<512, 512, 0, stream>>>(Pt, Vt, out);
}